// Round 5
// baseline (344.218 us; speedup 1.0000x reference)
//
#include <hip/hip_runtime.h>
#include <hip/hip_bf16.h>
#include <cstdint>

typedef __attribute__((ext_vector_type(8))) short short8;
typedef __attribute__((ext_vector_type(4))) float f32x4;
typedef __attribute__((ext_vector_type(4))) unsigned int u32x4;

// pack two floats as bf16 pair (RTNE), a in low 16, b in high 16
__device__ __forceinline__ uint32_t pk_bf16(float a, float b) {
    uint32_t ua = (uint32_t)__builtin_bit_cast(unsigned short, __float2bfloat16(a));
    uint32_t ub = (uint32_t)__builtin_bit_cast(unsigned short, __float2bfloat16(b));
    return ua | (ub << 16);
}
// split (a,b) into bf16 hi pair H and bf16 lo pair L (3-term split precision)
__device__ __forceinline__ void split_pair(float a, float b, uint32_t& H, uint32_t& L) {
    H = pk_bf16(a, b);
    float fa = __uint_as_float(H << 16);
    float fb = __uint_as_float(H & 0xffff0000u);
    L = pk_bf16(a - fa, b - fb);
}
__device__ __forceinline__ short8 mk8(uint32_t a, uint32_t b, uint32_t c, uint32_t d) {
    u32x4 v; v[0] = a; v[1] = b; v[2] = c; v[3] = d;
    return __builtin_bit_cast(short8, v);
}
__device__ __forceinline__ float bf16lo(uint32_t p) { return __uint_as_float(p << 16); }
__device__ __forceinline__ float bf16hi(uint32_t p) { return __uint_as_float(p & 0xffff0000u); }

// build B-frag pair (hi,lo) from two acc tiles (k-tiles 2kp, 2kp+1)
__device__ __forceinline__ void cvt_frag(f32x4 A, f32x4 Bv, short8& hi, short8& lo) {
    uint32_t h0, l0, h1, l1, h2, l2, h3, l3;
    split_pair(A[0],  A[1],  h0, l0);
    split_pair(A[2],  A[3],  h1, l1);
    split_pair(Bv[0], Bv[1], h2, l2);
    split_pair(Bv[2], Bv[3], h3, l3);
    hi = mk8(h0, h1, h2, h3);
    lo = mk8(l0, l1, l2, l3);
}

// ---------------- weight prep: fp32 W -> permuted-K bf16 hi/lo A-fragments ----------------
// k-slot (g,e) of k-step kp holds feature f = (2kp + (e>>2))*16 + 4g + (e&3).
// Layout: wf[(Lid*2+kp)*2 + plane][lane][mt][e]  (2048 elems per plane-frag)
__global__ void prep_weights(const float* __restrict__ cWh, const float* __restrict__ cWo,
                             const float* __restrict__ sWh, const float* __restrict__ sWo,
                             unsigned short* __restrict__ wf) {
    int t = blockIdx.x * 256 + threadIdx.x;  // 0..32767
    int e    = t & 7;
    int mt   = (t >> 3) & 3;
    int lane = (t >> 5) & 63;
    int kp   = (t >> 11) & 1;
    int L    = (t >> 12) & 7;
    const float* src = (L < 3)  ? cWh + L * 4096
                     : (L == 3) ? cWo
                     : (L < 7)  ? sWh + (L - 4) * 4096
                     :            sWo;
    int m = mt * 16 + (lane & 15);
    int k = (2 * kp + (e >> 2)) * 16 + 4 * (lane >> 4) + (e & 3);
    float w = src[m * 64 + k];
    uint32_t H, Lo;
    split_pair(w, w, H, Lo);
    int off = lane * 32 + mt * 8 + e;
    int fi = (L * 2 + kp) * 2;
    wf[fi * 2048 + off]        = (unsigned short)H;   // hi plane
    wf[(fi + 1) * 2048 + off]  = (unsigned short)Lo;  // lo plane
}

// ---------------- one MLP layer (16 samples/wave), all in registers ----------------
__device__ __forceinline__ void run_layer(const unsigned short* __restrict__ wf, int Lid,
                                          const float* __restrict__ bias, int lane, int g4,
                                          const short8 Bh[2], const short8 Bl[2],
                                          f32x4 acc[4]) {
#pragma unroll
    for (int mt = 0; mt < 4; ++mt)
        acc[mt] = *(const f32x4*)(bias + mt * 16 + g4);
#pragma unroll
    for (int kp = 0; kp < 2; ++kp) {
        short8 Ah[4], Al[4];
        const unsigned short* p = wf + (Lid * 2 + kp) * 4096 + lane * 32;
#pragma unroll
        for (int mt = 0; mt < 4; ++mt) {
            Ah[mt] = *(const short8*)(p + mt * 8);
            Al[mt] = *(const short8*)(p + 2048 + mt * 8);
        }
#pragma unroll
        for (int mt = 0; mt < 4; ++mt) {
            acc[mt] = __builtin_amdgcn_mfma_f32_16x16x32_bf16(Ah[mt], Bh[kp], acc[mt], 0, 0, 0);
            acc[mt] = __builtin_amdgcn_mfma_f32_16x16x32_bf16(Al[mt], Bh[kp], acc[mt], 0, 0, 0);
            acc[mt] = __builtin_amdgcn_mfma_f32_16x16x32_bf16(Ah[mt], Bl[kp], acc[mt], 0, 0, 0);
        }
    }
}

__device__ __forceinline__ void acc_to_B_relu(const f32x4 acc[4], short8 Bh[2], short8 Bl[2]) {
#pragma unroll
    for (int kp = 0; kp < 2; ++kp) {
        f32x4 a = acc[2 * kp], b = acc[2 * kp + 1];
#pragma unroll
        for (int i = 0; i < 4; ++i) { a[i] = fmaxf(a[i], 0.f); b[i] = fmaxf(b[i], 0.f); }
        cvt_frag(a, b, Bh[kp], Bl[kp]);
    }
}

// ---------------- main kernel: 1 wave = 16 rows, 4 waves/block, no LDS, no barriers ----------------
__global__ __launch_bounds__(256, 4)
void coupling_main(const float* __restrict__ x,
                   const float* __restrict__ cbh, const float* __restrict__ cbo,
                   const float* __restrict__ sbh, const float* __restrict__ sbo,
                   const unsigned short* __restrict__ wf,
                   float* __restrict__ y, float* __restrict__ logdet) {
    const int lane = threadIdx.x & 63;
    const int wid = threadIdx.x >> 6;
    const int c = lane & 15;
    const int g4 = (lane >> 4) * 4;
    const long row0 = (long)blockIdx.x * 64 + wid * 16;
    const float* xr = x + (row0 + c) * 128 + g4;
    float* yr = y + (row0 + c) * 128 + g4;

    // prologue: read x_masked once, passthrough to y[:, :64], build B0 frags (parked, 16 regs)
    short8 B0h[2], B0l[2];
#pragma unroll
    for (int kp = 0; kp < 2; ++kp) {
        f32x4 a = *(const f32x4*)(xr + (2 * kp) * 16);
        f32x4 b = *(const f32x4*)(xr + (2 * kp + 1) * 16);
        __builtin_nontemporal_store(a, (f32x4*)(yr + (2 * kp) * 16));
        __builtin_nontemporal_store(b, (f32x4*)(yr + (2 * kp + 1) * 16));
        cvt_frag(a, b, B0h[kp], B0l[kp]);
    }

    f32x4 acc[4];
    short8 Bh[2], Bl[2];

    // cond MLP (prep layer ids 0..3) -> shift (parked as packed bf16, 8 regs)
    run_layer(wf, 0, cbh,       lane, g4, B0h, B0l, acc);
    acc_to_B_relu(acc, Bh, Bl);
    run_layer(wf, 1, cbh + 64,  lane, g4, Bh, Bl, acc);
    acc_to_B_relu(acc, Bh, Bl);
    run_layer(wf, 2, cbh + 128, lane, g4, Bh, Bl, acc);
    acc_to_B_relu(acc, Bh, Bl);
    run_layer(wf, 3, cbo,       lane, g4, Bh, Bl, acc);
    uint2 shiftp[4];
#pragma unroll
    for (int mt = 0; mt < 4; ++mt) {
        shiftp[mt].x = pk_bf16(acc[mt][0], acc[mt][1]);
        shiftp[mt].y = pk_bf16(acc[mt][2], acc[mt][3]);
    }

    // scale MLP (ids 4..7) -> log_scale in acc
    run_layer(wf, 4, sbh,       lane, g4, B0h, B0l, acc);
    acc_to_B_relu(acc, Bh, Bl);
    run_layer(wf, 5, sbh + 64,  lane, g4, Bh, Bl, acc);
    acc_to_B_relu(acc, Bh, Bl);
    run_layer(wf, 6, sbh + 128, lane, g4, Bh, Bl, acc);
    acc_to_B_relu(acc, Bh, Bl);
    run_layer(wf, 7, sbo,       lane, g4, Bh, Bl, acc);

    // epilogue: y[:,64:] = x_t * exp(clip(ls,-5,3)) + shift ; logdet = sum(ls unclipped)
    float psum = 0.f;
#pragma unroll
    for (int mt = 0; mt < 4; ++mt) {
        f32x4 ls = acc[mt];
        psum += ls[0] + ls[1] + ls[2] + ls[3];
        f32x4 xt = *(const f32x4*)(xr + 64 + mt * 16);
        f32x4 o;
        o[0] = xt[0] * __expf(fminf(fmaxf(ls[0], -5.f), 3.f)) + bf16lo(shiftp[mt].x);
        o[1] = xt[1] * __expf(fminf(fmaxf(ls[1], -5.f), 3.f)) + bf16hi(shiftp[mt].x);
        o[2] = xt[2] * __expf(fminf(fmaxf(ls[2], -5.f), 3.f)) + bf16lo(shiftp[mt].y);
        o[3] = xt[3] * __expf(fminf(fmaxf(ls[3], -5.f), 3.f)) + bf16hi(shiftp[mt].y);
        __builtin_nontemporal_store(o, (f32x4*)(yr + 64 + mt * 16));
    }
    psum += __shfl_xor(psum, 16);
    psum += __shfl_xor(psum, 32);
    if ((lane >> 4) == 0) logdet[row0 + c] = psum;
}

extern "C" void kernel_launch(void* const* d_in, const int* in_sizes, int n_in,
                              void* d_out, int out_size, void* d_ws, size_t ws_size,
                              hipStream_t stream) {
    const float* x   = (const float*)d_in[0];
    const float* cWh = (const float*)d_in[1];
    const float* cbh = (const float*)d_in[2];
    const float* cWo = (const float*)d_in[3];
    const float* cbo = (const float*)d_in[4];
    const float* sWh = (const float*)d_in[5];
    const float* sbh = (const float*)d_in[6];
    const float* sWo = (const float*)d_in[7];
    const float* sbo = (const float*)d_in[8];

    const int B = in_sizes[0] / 128;  // 524288

    unsigned short* wf = (unsigned short*)d_ws;  // 8 layers * 2 kp * 2 planes * 2048 = 128 KB

    prep_weights<<<128, 256, 0, stream>>>(cWh, cWo, sWh, sWo, wf);

    float* y = (float*)d_out;
    float* logdet = y + (size_t)B * 128;
    coupling_main<<<B / 64, 256, 0, stream>>>(x, cbh, cbo, sbh, sbo, wf, y, logdet);
}

// Round 6
// 233.090 us; speedup vs baseline: 1.4768x; 1.4768x over previous
//
#include <hip/hip_runtime.h>
#include <hip/hip_bf16.h>
#include <cstdint>

typedef __attribute__((ext_vector_type(8))) short short8;
typedef __attribute__((ext_vector_type(4))) float f32x4;
typedef __attribute__((ext_vector_type(4))) unsigned int u32x4;

// pack two floats as bf16 pair (RTNE), a in low 16, b in high 16
__device__ __forceinline__ uint32_t pk_bf16(float a, float b) {
    uint32_t ua = (uint32_t)__builtin_bit_cast(unsigned short, __float2bfloat16(a));
    uint32_t ub = (uint32_t)__builtin_bit_cast(unsigned short, __float2bfloat16(b));
    return ua | (ub << 16);
}
// split (a,b) into bf16 hi pair H and bf16 lo pair L (3-term split precision)
__device__ __forceinline__ void split_pair(float a, float b, uint32_t& H, uint32_t& L) {
    H = pk_bf16(a, b);
    float fa = __uint_as_float(H << 16);
    float fb = __uint_as_float(H & 0xffff0000u);
    L = pk_bf16(a - fa, b - fb);
}
__device__ __forceinline__ short8 mk8(uint32_t a, uint32_t b, uint32_t c, uint32_t d) {
    u32x4 v; v[0] = a; v[1] = b; v[2] = c; v[3] = d;
    return __builtin_bit_cast(short8, v);
}
__device__ __forceinline__ float bf16lo(uint32_t p) { return __uint_as_float(p << 16); }
__device__ __forceinline__ float bf16hi(uint32_t p) { return __uint_as_float(p & 0xffff0000u); }

// build B-frag pair (hi,lo) from two acc tiles (k-tiles 2kp, 2kp+1)
__device__ __forceinline__ void cvt_frag(f32x4 A, f32x4 Bv, short8& hi, short8& lo) {
    uint32_t h0, l0, h1, l1, h2, l2, h3, l3;
    split_pair(A[0],  A[1],  h0, l0);
    split_pair(A[2],  A[3],  h1, l1);
    split_pair(Bv[0], Bv[1], h2, l2);
    split_pair(Bv[2], Bv[3], h3, l3);
    hi = mk8(h0, h1, h2, h3);
    lo = mk8(l0, l1, l2, l3);
}

// ---------------- weight prep: fp32 W -> permuted-K bf16 hi/lo A-fragments ----------------
// k-slot (g,e) of k-step kp holds feature f = (2kp + (e>>2))*16 + 4g + (e&3).
// Layout: wf[(Lid*2+kp)*2 + plane][lane][mt][e]  (2048 elems per plane-frag)
__global__ void prep_weights(const float* __restrict__ cWh, const float* __restrict__ cWo,
                             const float* __restrict__ sWh, const float* __restrict__ sWo,
                             unsigned short* __restrict__ wf) {
    int t = blockIdx.x * 256 + threadIdx.x;  // 0..32767
    int e    = t & 7;
    int mt   = (t >> 3) & 3;
    int lane = (t >> 5) & 63;
    int kp   = (t >> 11) & 1;
    int L    = (t >> 12) & 7;
    const float* src = (L < 3)  ? cWh + L * 4096
                     : (L == 3) ? cWo
                     : (L < 7)  ? sWh + (L - 4) * 4096
                     :            sWo;
    int m = mt * 16 + (lane & 15);
    int k = (2 * kp + (e >> 2)) * 16 + 4 * (lane >> 4) + (e & 3);
    float w = src[m * 64 + k];
    uint32_t H, Lo;
    split_pair(w, w, H, Lo);
    int off = lane * 32 + mt * 8 + e;
    int fi = (L * 2 + kp) * 2;
    wf[fi * 2048 + off]        = (unsigned short)H;   // hi plane
    wf[(fi + 1) * 2048 + off]  = (unsigned short)Lo;  // lo plane
}

// ---------------- one MLP layer (64 samples/wave), all in registers ----------------
__device__ __forceinline__ void run_layer(const unsigned short* __restrict__ wf, int Lid,
                                          const float* __restrict__ bias, int lane, int g4,
                                          const short8 Bh[2][4], const short8 Bl[2][4],
                                          f32x4 acc[4][4]) {
#pragma unroll
    for (int mt = 0; mt < 4; ++mt) {
        f32x4 bb = *(const f32x4*)(bias + mt * 16 + g4);
#pragma unroll
        for (int nt = 0; nt < 4; ++nt) acc[mt][nt] = bb;
    }
#pragma unroll
    for (int kp = 0; kp < 2; ++kp) {
        short8 Ah[4], Al[4];
        const unsigned short* p = wf + (Lid * 2 + kp) * 4096 + lane * 32;
#pragma unroll
        for (int mt = 0; mt < 4; ++mt) {
            Ah[mt] = *(const short8*)(p + mt * 8);
            Al[mt] = *(const short8*)(p + 2048 + mt * 8);
        }
#pragma unroll
        for (int nt = 0; nt < 4; ++nt)
#pragma unroll
            for (int mt = 0; mt < 4; ++mt) {
                acc[mt][nt] = __builtin_amdgcn_mfma_f32_16x16x32_bf16(Ah[mt], Bh[kp][nt], acc[mt][nt], 0, 0, 0);
                acc[mt][nt] = __builtin_amdgcn_mfma_f32_16x16x32_bf16(Al[mt], Bh[kp][nt], acc[mt][nt], 0, 0, 0);
                acc[mt][nt] = __builtin_amdgcn_mfma_f32_16x16x32_bf16(Ah[mt], Bl[kp][nt], acc[mt][nt], 0, 0, 0);
            }
    }
}

__device__ __forceinline__ void acc_to_B_relu(const f32x4 acc[4][4], short8 Bh[2][4], short8 Bl[2][4]) {
#pragma unroll
    for (int kp = 0; kp < 2; ++kp)
#pragma unroll
        for (int nt = 0; nt < 4; ++nt) {
            f32x4 a = acc[2 * kp][nt], b = acc[2 * kp + 1][nt];
#pragma unroll
            for (int i = 0; i < 4; ++i) { a[i] = fmaxf(a[i], 0.f); b[i] = fmaxf(b[i], 0.f); }
            cvt_frag(a, b, Bh[kp][nt], Bl[kp][nt]);
        }
}

// build B0 (x_masked) fragments straight from global; optionally write passthrough
template<bool WRITE_Y>
__device__ __forceinline__ void load_B0(const float* __restrict__ xr, float* __restrict__ yr,
                                        short8 Bh[2][4], short8 Bl[2][4]) {
#pragma unroll
    for (int nt = 0; nt < 4; ++nt) {
#pragma unroll
        for (int kp = 0; kp < 2; ++kp) {
            f32x4 a = *(const f32x4*)(xr + nt * 2048 + (2 * kp) * 16);
            f32x4 b = *(const f32x4*)(xr + nt * 2048 + (2 * kp + 1) * 16);
            if (WRITE_Y) {
                __builtin_nontemporal_store(a, (f32x4*)(yr + nt * 2048 + (2 * kp) * 16));
                __builtin_nontemporal_store(b, (f32x4*)(yr + nt * 2048 + (2 * kp + 1) * 16));
            }
            cvt_frag(a, b, Bh[kp][nt], Bl[kp][nt]);
        }
    }
}

// ---------------- main kernel: 1 wave = 64 rows, 1-wave blocks, shift parked in LDS ----------------
__global__ __launch_bounds__(64, 3)
void coupling_main(const float* __restrict__ x,
                   const float* __restrict__ cbh, const float* __restrict__ cbo,
                   const float* __restrict__ sbh, const float* __restrict__ sbo,
                   const unsigned short* __restrict__ wf,
                   float* __restrict__ y, float* __restrict__ logdet) {
    __shared__ uint2 shpark[16][64];  // 8 KB: shift parked as packed bf16
    const int lane = threadIdx.x;
    const int c = lane & 15;
    const int g4 = (lane >> 4) * 4;
    const long row0 = (long)blockIdx.x * 64;
    const float* xr = x + (row0 + c) * 128 + g4;
    float* yr = y + (row0 + c) * 128 + g4;

    f32x4 acc[4][4];
    short8 Bh[2][4], Bl[2][4];

    // prologue: read x_masked, passthrough to y[:, :64], build B0 (no reg parking)
    load_B0<true>(xr, yr, Bh, Bl);

    // cond MLP (prep layer ids 0..3) -> shift, parked in LDS as packed bf16
    run_layer(wf, 0, cbh,       lane, g4, Bh, Bl, acc);
    acc_to_B_relu(acc, Bh, Bl);
    run_layer(wf, 1, cbh + 64,  lane, g4, Bh, Bl, acc);
    acc_to_B_relu(acc, Bh, Bl);
    run_layer(wf, 2, cbh + 128, lane, g4, Bh, Bl, acc);
    acc_to_B_relu(acc, Bh, Bl);
    run_layer(wf, 3, cbo,       lane, g4, Bh, Bl, acc);
#pragma unroll
    for (int mt = 0; mt < 4; ++mt)
#pragma unroll
        for (int nt = 0; nt < 4; ++nt) {
            uint2 sp;
            sp.x = pk_bf16(acc[mt][nt][0], acc[mt][nt][1]);
            sp.y = pk_bf16(acc[mt][nt][2], acc[mt][nt][3]);
            shpark[mt * 4 + nt][lane] = sp;
        }

    // rebuild B0 from cache (x row is L2/L3-hot from the prologue read)
    load_B0<false>(xr, yr, Bh, Bl);

    // scale MLP (ids 4..7) -> log_scale in acc
    run_layer(wf, 4, sbh,       lane, g4, Bh, Bl, acc);
    acc_to_B_relu(acc, Bh, Bl);
    run_layer(wf, 5, sbh + 64,  lane, g4, Bh, Bl, acc);
    acc_to_B_relu(acc, Bh, Bl);
    run_layer(wf, 6, sbh + 128, lane, g4, Bh, Bl, acc);
    acc_to_B_relu(acc, Bh, Bl);
    run_layer(wf, 7, sbo,       lane, g4, Bh, Bl, acc);

    // epilogue: y[:,64:] = x_t * exp(clip(ls,-5,3)) + shift ; logdet = sum(ls unclipped)
    float pld0 = 0.f, pld1 = 0.f, pld2 = 0.f, pld3 = 0.f;
#pragma unroll
    for (int nt = 0; nt < 4; ++nt) {
        float psum = 0.f;
#pragma unroll
        for (int mt = 0; mt < 4; ++mt) {
            f32x4 ls = acc[mt][nt];
            psum += ls[0] + ls[1] + ls[2] + ls[3];
            f32x4 xt = *(const f32x4*)(xr + nt * 2048 + 64 + mt * 16);
            uint2 sp = shpark[mt * 4 + nt][lane];
            f32x4 o;
            o[0] = xt[0] * __expf(fminf(fmaxf(ls[0], -5.f), 3.f)) + bf16lo(sp.x);
            o[1] = xt[1] * __expf(fminf(fmaxf(ls[1], -5.f), 3.f)) + bf16hi(sp.x);
            o[2] = xt[2] * __expf(fminf(fmaxf(ls[2], -5.f), 3.f)) + bf16lo(sp.y);
            o[3] = xt[3] * __expf(fminf(fmaxf(ls[3], -5.f), 3.f)) + bf16hi(sp.y);
            __builtin_nontemporal_store(o, (f32x4*)(yr + nt * 2048 + 64 + mt * 16));
        }
        if (nt == 0) pld0 = psum; else if (nt == 1) pld1 = psum;
        else if (nt == 2) pld2 = psum; else pld3 = psum;
    }
#pragma unroll
    for (int nt = 0; nt < 4; ++nt) {
        float v = (nt == 0) ? pld0 : (nt == 1) ? pld1 : (nt == 2) ? pld2 : pld3;
        v += __shfl_xor(v, 16);
        v += __shfl_xor(v, 32);
        if ((lane >> 4) == 0) logdet[row0 + nt * 16 + c] = v;
    }
}

extern "C" void kernel_launch(void* const* d_in, const int* in_sizes, int n_in,
                              void* d_out, int out_size, void* d_ws, size_t ws_size,
                              hipStream_t stream) {
    const float* x   = (const float*)d_in[0];
    const float* cWh = (const float*)d_in[1];
    const float* cbh = (const float*)d_in[2];
    const float* cWo = (const float*)d_in[3];
    const float* cbo = (const float*)d_in[4];
    const float* sWh = (const float*)d_in[5];
    const float* sbh = (const float*)d_in[6];
    const float* sWo = (const float*)d_in[7];
    const float* sbo = (const float*)d_in[8];

    const int B = in_sizes[0] / 128;  // 524288

    unsigned short* wf = (unsigned short*)d_ws;  // 8 layers * 2 kp * 2 planes * 2048 = 128 KB

    prep_weights<<<128, 256, 0, stream>>>(cWh, cWo, sWh, sWo, wf);

    float* y = (float*)d_out;
    float* logdet = y + (size_t)B * 128;
    coupling_main<<<B / 64, 64, 0, stream>>>(x, cbh, cbo, sbh, sbo, wf, y, logdet);
}

// Round 8
// 173.723 us; speedup vs baseline: 1.9814x; 1.3417x over previous
//
#include <hip/hip_runtime.h>
#include <cstdint>

typedef __attribute__((ext_vector_type(8))) _Float16 half8;
typedef __attribute__((ext_vector_type(4))) _Float16 half4;
typedef __attribute__((ext_vector_type(4))) float f32x4;

// ---------------- weight prep: fp32 W -> permuted-K fp16 hi/lo A-fragments ----------------
// k-slot (g,e) of k-step kp holds feature f = (2kp + (e>>2))*16 + 4g + (e&3).
// Layout: wf[(Lid*2+kp)*2 + plane][lane][mt][e]  (2048 halves per plane-frag)
__global__ void prep_weights(const float* __restrict__ cWh, const float* __restrict__ cWo,
                             const float* __restrict__ sWh, const float* __restrict__ sWo,
                             _Float16* __restrict__ wf) {
    int t = blockIdx.x * 256 + threadIdx.x;  // 0..32767
    int e    = t & 7;
    int mt   = (t >> 3) & 3;
    int lane = (t >> 5) & 63;
    int kp   = (t >> 11) & 1;
    int L    = (t >> 12) & 7;
    const float* src = (L < 3)  ? cWh + L * 4096
                     : (L == 3) ? cWo
                     : (L < 7)  ? sWh + (L - 4) * 4096
                     :            sWo;
    int m = mt * 16 + (lane & 15);
    int k = (2 * kp + (e >> 2)) * 16 + 4 * (lane >> 4) + (e & 3);
    float w = src[m * 64 + k];
    _Float16 hi = (_Float16)w;            // RTNE hardware cvt
    _Float16 lo = (_Float16)(w - (float)hi);
    int off = lane * 32 + mt * 8 + e;
    int fi = (L * 2 + kp) * 2;
    wf[fi * 2048 + off]       = hi;
    wf[(fi + 1) * 2048 + off] = lo;
}

// build one fp16 B-fragment from two f32x4 acc tiles (k-tiles 2kp, 2kp+1), with optional relu
template<bool RELU>
__device__ __forceinline__ half8 cvt_frag(f32x4 a, f32x4 b) {
    half8 r;
#pragma unroll
    for (int i = 0; i < 4; ++i) {
        float va = RELU ? fmaxf(a[i], 0.f) : a[i];
        float vb = RELU ? fmaxf(b[i], 0.f) : b[i];
        r[i]     = (_Float16)va;
        r[i + 4] = (_Float16)vb;
    }
    return r;
}

// ---------------- one MLP layer (64 samples/wave): 2-term weights x 1-term activations ----------------
__device__ __forceinline__ void run_layer(const _Float16* __restrict__ wf, int Lid,
                                          const float* __restrict__ bias, int lane, int g4,
                                          const half8 B[2][4], f32x4 acc[4][4]) {
#pragma unroll
    for (int mt = 0; mt < 4; ++mt) {
        f32x4 bb = *(const f32x4*)(bias + mt * 16 + g4);
#pragma unroll
        for (int nt = 0; nt < 4; ++nt) acc[mt][nt] = bb;
    }
#pragma unroll
    for (int kp = 0; kp < 2; ++kp) {
        half8 Ah[4], Al[4];
        const _Float16* p = wf + (Lid * 2 + kp) * 4096 + lane * 32;
#pragma unroll
        for (int mt = 0; mt < 4; ++mt) {
            Ah[mt] = *(const half8*)(p + mt * 8);
            Al[mt] = *(const half8*)(p + 2048 + mt * 8);
        }
#pragma unroll
        for (int nt = 0; nt < 4; ++nt)
#pragma unroll
            for (int mt = 0; mt < 4; ++mt) {
                acc[mt][nt] = __builtin_amdgcn_mfma_f32_16x16x32_f16(Ah[mt], B[kp][nt], acc[mt][nt], 0, 0, 0);
                acc[mt][nt] = __builtin_amdgcn_mfma_f32_16x16x32_f16(Al[mt], B[kp][nt], acc[mt][nt], 0, 0, 0);
            }
    }
}

__device__ __forceinline__ void acc_to_B_relu(const f32x4 acc[4][4], half8 B[2][4]) {
#pragma unroll
    for (int kp = 0; kp < 2; ++kp)
#pragma unroll
        for (int nt = 0; nt < 4; ++nt)
            B[kp][nt] = cvt_frag<true>(acc[2 * kp][nt], acc[2 * kp + 1][nt]);
}

// ---------------- main kernel: 1 wave = 64 rows, 1-wave blocks, no LDS, no barriers ----------------
__global__ __launch_bounds__(64, 2)
void coupling_main(const float* __restrict__ x,
                   const float* __restrict__ cbh, const float* __restrict__ cbo,
                   const float* __restrict__ sbh, const float* __restrict__ sbo,
                   const _Float16* __restrict__ wf,
                   float* __restrict__ y, float* __restrict__ logdet) {
    const int lane = threadIdx.x;
    const int c = lane & 15;
    const int g4 = (lane >> 4) * 4;
    const long row0 = (long)blockIdx.x * 64;
    const float* xr = x + (row0 + c) * 128 + g4;
    float* yr = y + (row0 + c) * 128 + g4;

    // prologue: read x_masked once, passthrough to y[:, :64], build B0 frags (parked, 32 regs)
    half8 B0[2][4];
#pragma unroll
    for (int nt = 0; nt < 4; ++nt) {
        f32x4 v0 = *(const f32x4*)(xr + nt * 2048);
        f32x4 v1 = *(const f32x4*)(xr + nt * 2048 + 16);
        f32x4 v2 = *(const f32x4*)(xr + nt * 2048 + 32);
        f32x4 v3 = *(const f32x4*)(xr + nt * 2048 + 48);
        __builtin_nontemporal_store(v0, (f32x4*)(yr + nt * 2048));
        __builtin_nontemporal_store(v1, (f32x4*)(yr + nt * 2048 + 16));
        __builtin_nontemporal_store(v2, (f32x4*)(yr + nt * 2048 + 32));
        __builtin_nontemporal_store(v3, (f32x4*)(yr + nt * 2048 + 48));
        B0[0][nt] = cvt_frag<false>(v0, v1);
        B0[1][nt] = cvt_frag<false>(v2, v3);
    }

    f32x4 acc[4][4];
    half8 B[2][4];

    // cond MLP (ids 0..3) -> shift (parked as fp16, 32 regs)
    run_layer(wf, 0, cbh,       lane, g4, B0, acc);
    acc_to_B_relu(acc, B);
    run_layer(wf, 1, cbh + 64,  lane, g4, B, acc);
    acc_to_B_relu(acc, B);
    run_layer(wf, 2, cbh + 128, lane, g4, B, acc);
    acc_to_B_relu(acc, B);
    run_layer(wf, 3, cbo,       lane, g4, B, acc);
    half4 shp[4][4];
#pragma unroll
    for (int mt = 0; mt < 4; ++mt)
#pragma unroll
        for (int nt = 0; nt < 4; ++nt) {
            half4 s;
#pragma unroll
            for (int i = 0; i < 4; ++i) s[i] = (_Float16)acc[mt][nt][i];
            shp[mt][nt] = s;
        }

    // scale MLP (ids 4..7) -> log_scale in acc
    run_layer(wf, 4, sbh,       lane, g4, B0, acc);
    acc_to_B_relu(acc, B);
    run_layer(wf, 5, sbh + 64,  lane, g4, B, acc);
    acc_to_B_relu(acc, B);
    run_layer(wf, 6, sbh + 128, lane, g4, B, acc);
    acc_to_B_relu(acc, B);
    run_layer(wf, 7, sbo,       lane, g4, B, acc);

    // epilogue: y[:,64:] = x_t * exp(clip(ls,-5,3)) + shift ; logdet = sum(ls unclipped)
    float pld0 = 0.f, pld1 = 0.f, pld2 = 0.f, pld3 = 0.f;
#pragma unroll
    for (int nt = 0; nt < 4; ++nt) {
        float psum = 0.f;
#pragma unroll
        for (int mt = 0; mt < 4; ++mt) {
            f32x4 ls = acc[mt][nt];
            psum += ls[0] + ls[1] + ls[2] + ls[3];
            f32x4 xt = *(const f32x4*)(xr + nt * 2048 + 64 + mt * 16);
            half4 sp = shp[mt][nt];
            f32x4 o;
#pragma unroll
            for (int i = 0; i < 4; ++i) {
                float cl = fminf(fmaxf(ls[i], -5.f), 3.f);
                o[i] = xt[i] * __expf(cl) + (float)sp[i];
            }
            __builtin_nontemporal_store(o, (f32x4*)(yr + nt * 2048 + 64 + mt * 16));
        }
        if (nt == 0) pld0 = psum; else if (nt == 1) pld1 = psum;
        else if (nt == 2) pld2 = psum; else pld3 = psum;
    }
#pragma unroll
    for (int nt = 0; nt < 4; ++nt) {
        float v = (nt == 0) ? pld0 : (nt == 1) ? pld1 : (nt == 2) ? pld2 : pld3;
        v += __shfl_xor(v, 16);
        v += __shfl_xor(v, 32);
        if ((lane >> 4) == 0) logdet[row0 + nt * 16 + c] = v;
    }
}

extern "C" void kernel_launch(void* const* d_in, const int* in_sizes, int n_in,
                              void* d_out, int out_size, void* d_ws, size_t ws_size,
                              hipStream_t stream) {
    const float* x   = (const float*)d_in[0];
    const float* cWh = (const float*)d_in[1];
    const float* cbh = (const float*)d_in[2];
    const float* cWo = (const float*)d_in[3];
    const float* cbo = (const float*)d_in[4];
    const float* sWh = (const float*)d_in[5];
    const float* sbh = (const float*)d_in[6];
    const float* sWo = (const float*)d_in[7];
    const float* sbo = (const float*)d_in[8];

    const int B = in_sizes[0] / 128;  // 524288

    _Float16* wf = (_Float16*)d_ws;  // 8 layers * 2 kp * 2 planes * 2048 halves = 128 KB

    prep_weights<<<128, 256, 0, stream>>>(cWh, cWo, sWh, sWo, wf);

    float* y = (float*)d_out;
    float* logdet = y + (size_t)B * 128;
    coupling_main<<<B / 64, 64, 0, stream>>>(x, cbh, cbo, sbh, sbo, wf, y, logdet);
}